// Round 1
// baseline (741.161 us; speedup 1.0000x reference)
//
#include <hip/hip_runtime.h>
#include <hip/hip_bf16.h>
#include <stdint.h>

#define NB 16
#define NPT 2048
#define NS 512
#define NK 32
#define PTOT (NB*NS*NK)   // 262144 positions
#define C_IN 67
#define EPSV 1e-5f

// ws layout (float indices)
#define WS_NEWXYZ 0                       // B*S*3 = 24576
#define WS_GIDX   24576                   // ints, 262144
#define WS_STATS  (24576+262144)          // 1024 floats (sums + affine, 3 layers)
#define WS_PTS_T  294912                  // B*N*64 = 2097152
#define WS_Y2     4194304                 // 64*PTOT = 16777216
#define WS_Y1     (4194304+16777216)      // 64*PTOT
#define WS_Y3     WS_Y1                   // overlaps y1 (dead), 128*PTOT

// ---------------- FPS ----------------
__global__ __launch_bounds__(512) void fps_kernel(const float* __restrict__ xyz,
                                                  float* __restrict__ nxyz,
                                                  float* __restrict__ out0)
{
  __shared__ float lx[NPT], ly[NPT], lz[NPT];
  __shared__ unsigned long long warr[2][8];
  const int b = blockIdx.x;
  const int tid = threadIdx.x;
  const float* xb = xyz + (size_t)b*3*NPT;
  float px[4], py[4], pz[4], dist[4];
  int pn[4];
  for (int j=0;j<4;j++){
    int n = j*512 + tid;
    float x = xb[n], y = xb[NPT+n], z = xb[2*NPT+n];
    lx[n]=x; ly[n]=y; lz[n]=z;
    px[j]=x; py[j]=y; pz[j]=z; dist[j]=1e10f; pn[j]=n;
  }
  __syncthreads();
  float cx = lx[0], cy = ly[0], cz = lz[0];
  if (tid==0){
    float* np_ = nxyz + (size_t)b*NS*3;
    np_[0]=cx; np_[1]=cy; np_[2]=cz;
    float* ob = out0 + (size_t)b*3*NS;
    ob[0]=cx; ob[NS]=cy; ob[2*NS]=cz;
  }
  const int lane = tid & 63, wid = tid >> 6;
  for (int t=1;t<NS;t++){
    unsigned long long best = 0ull;
    #pragma unroll
    for (int j=0;j<4;j++){
      float dx = __fsub_rn(px[j], cx);
      float dy = __fsub_rn(py[j], cy);
      float dz = __fsub_rn(pz[j], cz);
      float d  = __fadd_rn(__fadd_rn(__fmul_rn(dx,dx),__fmul_rn(dy,dy)),__fmul_rn(dz,dz));
      float dd = fminf(dist[j], d);
      dist[j] = dd;
      unsigned long long key = (((unsigned long long)__float_as_uint(dd))<<32) | (unsigned)(~pn[j]);
      best = best > key ? best : key;
    }
    #pragma unroll
    for (int off=32; off>0; off>>=1){
      unsigned long long o = __shfl_xor(best, off, 64);
      best = best > o ? best : o;
    }
    if (lane==0) warr[t&1][wid] = best;
    __syncthreads();
    unsigned long long m = warr[t&1][0];
    #pragma unroll
    for (int w=1;w<8;w++){ unsigned long long v = warr[t&1][w]; m = m > v ? m : v; }
    int n = (int)(~(unsigned)m);   // recover index (first-max tie-break via ~idx)
    cx = lx[n]; cy = ly[n]; cz = lz[n];
    if (tid==0){
      float* np_ = nxyz + ((size_t)b*NS + t)*3;
      np_[0]=cx; np_[1]=cy; np_[2]=cz;
      float* ob = out0 + (size_t)b*3*NS + t;
      ob[0]=cx; ob[NS]=cy; ob[2*NS]=cz;
    }
  }
}

// ---------------- ball query: one wave per group ----------------
__global__ __launch_bounds__(256) void ballq_kernel(const float* __restrict__ xyz,
                                                    const float* __restrict__ nxyz,
                                                    int* __restrict__ gidx)
{
  const int g = blockIdx.x*4 + (threadIdx.x>>6);
  const int lane = threadIdx.x & 63;
  const int b = g >> 9;
  const float* xb = xyz + (size_t)b*3*NPT;
  const float* c = nxyz + (size_t)g*3;
  const float cx = c[0], cy = c[1], cz = c[2];
  const float r2 = 0.2f*0.2f;
  int cnt = 0; int first = 0;
  int* out = gidx + (size_t)g*NK;
  for (int ch=0; ch<NPT/64 && cnt<NK; ch++){
    int n = ch*64 + lane;
    float dx = __fsub_rn(cx, xb[n]);
    float dy = __fsub_rn(cy, xb[NPT+n]);
    float dz = __fsub_rn(cz, xb[2*NPT+n]);
    float d  = __fadd_rn(__fadd_rn(__fmul_rn(dx,dx),__fmul_rn(dy,dy)),__fmul_rn(dz,dz));
    bool in = (d <= r2);
    unsigned long long mask = __ballot(in);
    if (mask){
      if (cnt==0) first = ch*64 + (__ffsll((unsigned long long)mask)-1);
      if (in){
        int pos = cnt + __popcll(mask & ((1ull<<lane)-1ull));
        if (pos < NK) out[pos] = n;
      }
      cnt += __popcll(mask);
    }
  }
  if (cnt < NK && lane >= cnt && lane < NK) out[lane] = first;
}

// ---------------- transpose points (B,64,N) -> (B,N,64) ----------------
__global__ __launch_bounds__(256) void transpose_kernel(const float* __restrict__ pts,
                                                        float* __restrict__ pts_t)
{
  __shared__ float tile[64][65];
  const int blk = blockIdx.x;          // B * N/64 = 512
  const int b = blk >> 5;
  const int n0 = (blk & 31) * 64;
  const int lane = threadIdx.x & 63;
  const int row4 = threadIdx.x >> 6;
  const float* src = pts + (size_t)b*64*NPT;
  #pragma unroll
  for (int r=0; r<16; r++){
    int cc = r*4 + row4;
    tile[cc][lane] = src[(size_t)cc*NPT + n0 + lane];
  }
  __syncthreads();
  float* dst = pts_t + ((size_t)b*NPT + n0)*64;
  #pragma unroll
  for (int r=0; r<16; r++){
    int nn = r*4 + row4;
    dst[(size_t)nn*64 + lane] = tile[lane][nn];
  }
}

// ---------------- conv1: gather + 67->64 ----------------
__global__ __launch_bounds__(256) void conv1_kernel(const float* __restrict__ xyz,
    const float* __restrict__ pts_t, const int* __restrict__ gidx,
    const float* __restrict__ nxyz, const float* __restrict__ Wt,
    const float* __restrict__ bias, float* __restrict__ y)
{
  const int p = blockIdx.x*256 + threadIdx.x;
  const int bs = p >> 5;
  const int b = p >> 14;
  const int n = gidx[p];
  float x[C_IN];
  {
    const float* xb = xyz + (size_t)b*3*NPT;
    const float* cc = nxyz + (size_t)bs*3;
    x[0] = xb[n]        - cc[0];
    x[1] = xb[NPT+n]    - cc[1];
    x[2] = xb[2*NPT+n]  - cc[2];
    const float4* pr = (const float4*)(pts_t + ((size_t)b*NPT + n)*64);
    #pragma unroll
    for (int q=0;q<16;q++){
      float4 v = pr[q];
      x[3+4*q]=v.x; x[4+4*q]=v.y; x[5+4*q]=v.z; x[6+4*q]=v.w;
    }
  }
  #pragma unroll 1
  for (int o=0;o<64;o+=4){
    float a0=bias[o+0], a1=bias[o+1], a2=bias[o+2], a3=bias[o+3];
    #pragma unroll
    for (int c=0;c<C_IN;c++){
      float xv = x[c];
      a0 = fmaf(Wt[(o+0)*C_IN+c], xv, a0);
      a1 = fmaf(Wt[(o+1)*C_IN+c], xv, a1);
      a2 = fmaf(Wt[(o+2)*C_IN+c], xv, a2);
      a3 = fmaf(Wt[(o+3)*C_IN+c], xv, a3);
    }
    y[(size_t)(o+0)*PTOT+p]=a0; y[(size_t)(o+1)*PTOT+p]=a1;
    y[(size_t)(o+2)*PTOT+p]=a2; y[(size_t)(o+3)*PTOT+p]=a3;
  }
}

// ---------------- convN: affine+relu on input, CIN->COUT ----------------
template<int CINT, int COUT>
__global__ __launch_bounds__(256) void convN_kernel(const float* __restrict__ yin,
    const float* __restrict__ affA, const float* __restrict__ affB,
    const float* __restrict__ Wt, const float* __restrict__ bias,
    float* __restrict__ yout)
{
  const int p = blockIdx.x*256 + threadIdx.x;
  float x[CINT];
  #pragma unroll
  for (int c=0;c<CINT;c++){
    float v = yin[(size_t)c*PTOT + p];
    x[c] = fmaxf(fmaf(v, affA[c], affB[c]), 0.f);
  }
  #pragma unroll 1
  for (int o=0;o<COUT;o+=4){
    float a0=bias[o+0], a1=bias[o+1], a2=bias[o+2], a3=bias[o+3];
    #pragma unroll
    for (int c=0;c<CINT;c++){
      float xv = x[c];
      a0 = fmaf(Wt[(o+0)*CINT+c], xv, a0);
      a1 = fmaf(Wt[(o+1)*CINT+c], xv, a1);
      a2 = fmaf(Wt[(o+2)*CINT+c], xv, a2);
      a3 = fmaf(Wt[(o+3)*CINT+c], xv, a3);
    }
    yout[(size_t)(o+0)*PTOT+p]=a0; yout[(size_t)(o+1)*PTOT+p]=a1;
    yout[(size_t)(o+2)*PTOT+p]=a2; yout[(size_t)(o+3)*PTOT+p]=a3;
  }
}

// ---------------- per-channel sum / sumsq ----------------
__global__ __launch_bounds__(256) void stats_kernel(const float* __restrict__ y,
                                                    float* __restrict__ sum,
                                                    float* __restrict__ sumsq)
{
  const int c = blockIdx.x;
  const float* yc = y + (size_t)c*PTOT + (size_t)blockIdx.y*8192;
  float s=0.f, s2=0.f;
  #pragma unroll 4
  for (int it=0; it<32; it++){
    float v = yc[it*256 + threadIdx.x];
    s += v; s2 = fmaf(v, v, s2);
  }
  #pragma unroll
  for (int off=32; off>0; off>>=1){ s += __shfl_down(s,off,64); s2 += __shfl_down(s2,off,64); }
  __shared__ float rs[4], rs2[4];
  const int lane = threadIdx.x&63, wid = threadIdx.x>>6;
  if (lane==0){ rs[wid]=s; rs2[wid]=s2; }
  __syncthreads();
  if (threadIdx.x==0){
    atomicAdd(sum+c,   rs[0]+rs[1]+rs[2]+rs[3]);
    atomicAdd(sumsq+c, rs2[0]+rs2[1]+rs2[2]+rs2[3]);
  }
}

__global__ void affine_kernel(const float* __restrict__ sum, const float* __restrict__ sumsq,
                              const float* __restrict__ g, const float* __restrict__ bt,
                              float* __restrict__ affA, float* __restrict__ affB, int C)
{
  int c = threadIdx.x;
  if (c < C){
    float mean = sum[c] * (1.f/PTOT);
    float var  = sumsq[c] * (1.f/PTOT) - mean*mean;
    float a = g[c] * rsqrtf(var + EPSV);
    affA[c] = a;
    affB[c] = fmaf(-mean, a, bt[c]);
  }
}

// ---------------- maxpool over K with affine+relu ----------------
__global__ __launch_bounds__(256) void maxpool_kernel(const float* __restrict__ y3,
    const float* __restrict__ affA, const float* __restrict__ affB,
    float* __restrict__ out)
{
  const int i = blockIdx.x*256 + threadIdx.x;  // (b*128+c)*512 + s
  const int c = (i >> 9) & 127;
  const int bs = (i >> 16)*512 + (i & 511);    // b*512+s
  const float a = affA[c], bb = affB[c];
  const float4* row = (const float4*)(y3 + (size_t)c*PTOT + (size_t)bs*32);
  float m = -1e30f;
  #pragma unroll
  for (int q=0;q<8;q++){
    float4 v = row[q];
    m = fmaxf(m, fmaxf(fmaxf(fmaf(v.x,a,bb), fmaf(v.y,a,bb)),
                       fmaxf(fmaf(v.z,a,bb), fmaf(v.w,a,bb))));
  }
  out[i] = fmaxf(m, 0.f);
}

__global__ void zero_kernel(float* p){ p[blockIdx.x*256 + threadIdx.x] = 0.f; }

extern "C" void kernel_launch(void* const* d_in, const int* in_sizes, int n_in,
                              void* d_out, int out_size, void* d_ws, size_t ws_size,
                              hipStream_t stream) {
  const float* xyz = (const float*)d_in[0];
  const float* pts = (const float*)d_in[1];
  const float* w0  = (const float*)d_in[2];
  const float* b0  = (const float*)d_in[3];
  const float* g0  = (const float*)d_in[4];
  const float* bt0 = (const float*)d_in[5];
  const float* w1  = (const float*)d_in[6];
  const float* b1  = (const float*)d_in[7];
  const float* g1  = (const float*)d_in[8];
  const float* bt1 = (const float*)d_in[9];
  const float* w2  = (const float*)d_in[10];
  const float* b2  = (const float*)d_in[11];
  const float* g2  = (const float*)d_in[12];
  const float* bt2 = (const float*)d_in[13];
  float* out = (float*)d_out;
  float* ws  = (float*)d_ws;

  float* nxyz  = ws + WS_NEWXYZ;
  int*   gidx  = (int*)(ws + WS_GIDX);
  float* st    = ws + WS_STATS;
  float* sum0=st,     *sq0=st+64,  *aA0=st+128, *aB0=st+192;
  float* sum1=st+256, *sq1=st+320, *aA1=st+384, *aB1=st+448;
  float* sum2=st+512, *sq2=st+640, *aA2=st+768, *aB2=st+896;
  float* pts_t = ws + WS_PTS_T;
  float* y2 = ws + WS_Y2;
  float* y1 = ws + WS_Y1;
  float* y3 = ws + WS_Y3;

  zero_kernel<<<4,256,0,stream>>>(st);
  transpose_kernel<<<512,256,0,stream>>>(pts, pts_t);
  fps_kernel<<<NB,512,0,stream>>>(xyz, nxyz, out);
  ballq_kernel<<<2048,256,0,stream>>>(xyz, nxyz, gidx);
  conv1_kernel<<<PTOT/256,256,0,stream>>>(xyz, pts_t, gidx, nxyz, w0, b0, y1);
  stats_kernel<<<dim3(64,32),256,0,stream>>>(y1, sum0, sq0);
  affine_kernel<<<1,64,0,stream>>>(sum0, sq0, g0, bt0, aA0, aB0, 64);
  convN_kernel<64,64><<<PTOT/256,256,0,stream>>>(y1, aA0, aB0, w1, b1, y2);
  stats_kernel<<<dim3(64,32),256,0,stream>>>(y2, sum1, sq1);
  affine_kernel<<<1,64,0,stream>>>(sum1, sq1, g1, bt1, aA1, aB1, 64);
  convN_kernel<64,128><<<PTOT/256,256,0,stream>>>(y2, aA1, aB1, w2, b2, y3);
  stats_kernel<<<dim3(128,32),256,0,stream>>>(y3, sum2, sq2);
  affine_kernel<<<1,128,0,stream>>>(sum2, sq2, g2, bt2, aA2, aB2, 128);
  maxpool_kernel<<<4096,256,0,stream>>>(y3, aA2, aB2, out + NB*3*NS);
}